// Round 10
// baseline (639.462 us; speedup 1.0000x reference)
//
#include <hip/hip_runtime.h>

#define D_IN 64
#define D_H 128
#define L_STEPS 16
#define ROWS_PER_BLOCK 32
#define THREADS 256

typedef float f32x4 __attribute__((ext_vector_type(4)));

// ---------------------------------------------------------------------------
// Kernel A — bit-exact numpy f32 GEMM chains.
// Both stages are 4-row x 4-col register tiles, k ascending, one sequential
// FMA chain per output element (bit-identical to the verified round-6 kernel,
// only the thread->element mapping changed).
//   stage 1: h = x @ W_syn + b_syn   (k = 0..63)
//   stage 2: I = h @ W_in  + b_in    (k = 0..127), written to workspace.
// ---------------------------------------------------------------------------
__global__ __launch_bounds__(THREADS) void snn_gemm(
        const float* __restrict__ x,
        const float* __restrict__ W_syn,
        const float* __restrict__ b_syn,
        const float* __restrict__ W_in,
        const float* __restrict__ b_in,
        float* __restrict__ I_out,
        int B) {
    __shared__ float xs[ROWS_PER_BLOCK][D_IN];    // 8 KB
    __shared__ float hs[ROWS_PER_BLOCK][D_H];     // 16 KB

    const int tid = threadIdx.x;
    const long long row0 = (long long)blockIdx.x * ROWS_PER_BLOCK;

    // cooperative x block load (2048 floats = 512 float4)
    {
        const float4* src = (const float4*)(x + row0 * D_IN);
        float4* dst = (float4*)&xs[0][0];
        dst[tid]       = src[tid];
        dst[tid + 256] = src[tid + 256];
    }
    __syncthreads();

    const int h0 = (tid & 31) * 4;    // col quad
    const int rg = (tid >> 5) * 4;    // row group of 4

    // ---- stage 1: 4x4 tile, sequential chain over k = 0..63 ----
    {
        float acc1[4][4];
#pragma unroll
        for (int rr = 0; rr < 4; ++rr)
#pragma unroll
            for (int q = 0; q < 4; ++q) acc1[rr][q] = 0.0f;

#pragma unroll 4
        for (int k4 = 0; k4 < 16; ++k4) {
            float xrow[4][4];
#pragma unroll
            for (int rr = 0; rr < 4; ++rr) {
                float4 x4 = *(const float4*)&xs[rg + rr][4 * k4];
                xrow[rr][0] = x4.x; xrow[rr][1] = x4.y;
                xrow[rr][2] = x4.z; xrow[rr][3] = x4.w;
            }
#pragma unroll
            for (int q4 = 0; q4 < 4; ++q4) {               // k ascending
                const int k = 4 * k4 + q4;
                float4 w = *(const float4*)&W_syn[k * D_H + h0];
#pragma unroll
                for (int rr = 0; rr < 4; ++rr) {
                    const float xv = xrow[rr][q4];
                    acc1[rr][0] = __fmaf_rn(xv, w.x, acc1[rr][0]);
                    acc1[rr][1] = __fmaf_rn(xv, w.y, acc1[rr][1]);
                    acc1[rr][2] = __fmaf_rn(xv, w.z, acc1[rr][2]);
                    acc1[rr][3] = __fmaf_rn(xv, w.w, acc1[rr][3]);
                }
            }
        }
        const float4 bs = *(const float4*)&b_syn[h0];
#pragma unroll
        for (int rr = 0; rr < 4; ++rr) {
            float4 hv;
            hv.x = __fadd_rn(acc1[rr][0], bs.x);           // numpy's separate +b_syn
            hv.y = __fadd_rn(acc1[rr][1], bs.y);
            hv.z = __fadd_rn(acc1[rr][2], bs.z);
            hv.w = __fadd_rn(acc1[rr][3], bs.w);
            *(float4*)&hs[rg + rr][h0] = hv;
        }
    }
    __syncthreads();

    // ---- stage 2: 4x4 tile, sequential chain over j = 0..127 ----
    float acc[4][4];
#pragma unroll
    for (int rr = 0; rr < 4; ++rr)
#pragma unroll
        for (int q = 0; q < 4; ++q) acc[rr][q] = 0.0f;

#pragma unroll 8
    for (int j4 = 0; j4 < 32; ++j4) {
        float hrow[4][4];
#pragma unroll
        for (int rr = 0; rr < 4; ++rr) {
            float4 h4 = *(const float4*)&hs[rg + rr][4 * j4];
            hrow[rr][0] = h4.x; hrow[rr][1] = h4.y;
            hrow[rr][2] = h4.z; hrow[rr][3] = h4.w;
        }
#pragma unroll
        for (int q4 = 0; q4 < 4; ++q4) {                   // j ascending
            const int j = 4 * j4 + q4;
            float4 w = *(const float4*)&W_in[j * D_H + h0];
#pragma unroll
            for (int rr = 0; rr < 4; ++rr) {
                const float hv = hrow[rr][q4];
                acc[rr][0] = __fmaf_rn(hv, w.x, acc[rr][0]);
                acc[rr][1] = __fmaf_rn(hv, w.y, acc[rr][1]);
                acc[rr][2] = __fmaf_rn(hv, w.z, acc[rr][2]);
                acc[rr][3] = __fmaf_rn(hv, w.w, acc[rr][3]);
            }
        }
    }

    const float4 bi = *(const float4*)&b_in[h0];
#pragma unroll
    for (int rr = 0; rr < 4; ++rr) {
        float4 Iv;
        Iv.x = __fadd_rn(acc[rr][0], bi.x);                // numpy's separate +b_in
        Iv.y = __fadd_rn(acc[rr][1], bi.y);
        Iv.z = __fadd_rn(acc[rr][2], bi.z);
        Iv.w = __fadd_rn(acc[rr][3], bi.w);
        *(float4*)(I_out + (size_t)(row0 + rg + rr) * D_H + (size_t)h0) = Iv;
    }
}

// ---------------------------------------------------------------------------
// Kernel B — streaming recurrence. Plain (write-back) coalesced f32x4 stores;
// identical uncontracted f32 arithmetic.
// ---------------------------------------------------------------------------
__global__ __launch_bounds__(256) void snn_recur(
        const float* __restrict__ I,
        float* __restrict__ out,
        int B) {
    const size_t BH = (size_t)B * D_H;
    const size_t nquads = BH >> 2;
    const size_t stride = (size_t)gridDim.x * 256u;
    float* __restrict__ vout = out + (size_t)L_STEPS * BH;

    for (size_t q = (size_t)blockIdx.x * 256u + threadIdx.x; q < nquads; q += stride) {
        const f32x4 I4 = ((const f32x4*)I)[q];
        const float I0 = I4.x, I1 = I4.y, I2 = I4.z, I3 = I4.w;
        float v0 = 0.f, v1 = 0.f, v2 = 0.f, v3 = 0.f;
        float s0 = 0.f, s1 = 0.f, s2 = 0.f, s3 = 0.f;
        float* base = out + 4 * q;
#pragma unroll
        for (int t = 0; t < L_STEPS; ++t) {
            v0 = __fsub_rn(__fadd_rn(__fmul_rn(0.9f, v0), I0), s0);
            v1 = __fsub_rn(__fadd_rn(__fmul_rn(0.9f, v1), I1), s1);
            v2 = __fsub_rn(__fadd_rn(__fmul_rn(0.9f, v2), I2), s2);
            v3 = __fsub_rn(__fadd_rn(__fmul_rn(0.9f, v3), I3), s3);
            s0 = (v0 >= 1.0f) ? 1.0f : 0.0f;
            s1 = (v1 >= 1.0f) ? 1.0f : 0.0f;
            s2 = (v2 >= 1.0f) ? 1.0f : 0.0f;
            s3 = (v3 >= 1.0f) ? 1.0f : 0.0f;
            f32x4 s4 = {s0, s1, s2, s3};
            *(f32x4*)(base + (size_t)t * BH) = s4;
        }
        f32x4 v4 = {v0, v1, v2, v3};
        *(f32x4*)(vout + 4 * q) = v4;
    }
}

extern "C" void kernel_launch(void* const* d_in, const int* in_sizes, int n_in,
                              void* d_out, int out_size, void* d_ws, size_t ws_size,
                              hipStream_t stream) {
    const float* x     = (const float*)d_in[0];
    const float* W_syn = (const float*)d_in[1];
    const float* b_syn = (const float*)d_in[2];
    const float* W_in  = (const float*)d_in[3];
    const float* b_in  = (const float*)d_in[4];
    float* out = (float*)d_out;

    const int B = in_sizes[0] / D_IN;   // 65536
    float* I = (float*)d_ws;            // B*128 f32 = 33.5 MB scratch

    snn_gemm<<<dim3(B / ROWS_PER_BLOCK), dim3(THREADS), 0, stream>>>(
        x, W_syn, b_syn, W_in, b_in, I, B);

    snn_recur<<<dim3(2048), dim3(256), 0, stream>>>(I, out, B);
}

// Round 11
// 613.014 us; speedup vs baseline: 1.0431x; 1.0431x over previous
//
#include <hip/hip_runtime.h>

#define D_IN 64
#define D_H 128
#define L_STEPS 16
#define ROWS_PER_BLOCK 32
#define THREADS 256

typedef float f32x4 __attribute__((ext_vector_type(4)));

// ---------------------------------------------------------------------------
// Fused lean kernel — bit-exact numpy f32 emulation (chains verified R6/R9/R10):
//   stage 1: h = x @ W_syn + b_syn   (per-element sequential FMA chain, k asc)
//   stage 2: I = h @ W_in  + b_in    (same), kept in REGISTERS
//   16x:     v = (0.9f*v + I) - s ;  s = (v >= 1.0f)   (uncontracted f32)
// Outputs f32: spikes [16,B,128] then v_final [B,128].
// Block: 32 rows, 256 threads; thread: 4 rows x 4 cols (one f32x4 quad/row).
// ~64-80 VGPR -> high occupancy through the store phase; 24 KB LDS.
// ---------------------------------------------------------------------------
__global__ __launch_bounds__(THREADS) void snn_fused(
        const float* __restrict__ x,
        const float* __restrict__ W_syn,
        const float* __restrict__ b_syn,
        const float* __restrict__ W_in,
        const float* __restrict__ b_in,
        float* __restrict__ out,
        int B) {
    __shared__ float xs[ROWS_PER_BLOCK][D_IN];    // 8 KB
    __shared__ float hs[ROWS_PER_BLOCK][D_H];     // 16 KB

    const int tid = threadIdx.x;
    const long long row0 = (long long)blockIdx.x * ROWS_PER_BLOCK;

    // cooperative x block load (2048 floats = 512 float4)
    {
        const float4* src = (const float4*)(x + row0 * D_IN);
        float4* dst = (float4*)&xs[0][0];
        dst[tid]       = src[tid];
        dst[tid + 256] = src[tid + 256];
    }
    __syncthreads();

    const int h0 = (tid & 31) * 4;    // col quad
    const int rg = (tid >> 5) * 4;    // row group of 4

    // ---- stage 1: 4x4 tile, sequential chain over k = 0..63 ----
    {
        float acc1[4][4];
#pragma unroll
        for (int rr = 0; rr < 4; ++rr)
#pragma unroll
            for (int q = 0; q < 4; ++q) acc1[rr][q] = 0.0f;

#pragma unroll 4
        for (int k4 = 0; k4 < 16; ++k4) {
            float xrow[4][4];
#pragma unroll
            for (int rr = 0; rr < 4; ++rr) {
                float4 x4 = *(const float4*)&xs[rg + rr][4 * k4];
                xrow[rr][0] = x4.x; xrow[rr][1] = x4.y;
                xrow[rr][2] = x4.z; xrow[rr][3] = x4.w;
            }
#pragma unroll
            for (int q4 = 0; q4 < 4; ++q4) {               // k ascending
                const int k = 4 * k4 + q4;
                float4 w = *(const float4*)&W_syn[k * D_H + h0];
#pragma unroll
                for (int rr = 0; rr < 4; ++rr) {
                    const float xv = xrow[rr][q4];
                    acc1[rr][0] = __fmaf_rn(xv, w.x, acc1[rr][0]);
                    acc1[rr][1] = __fmaf_rn(xv, w.y, acc1[rr][1]);
                    acc1[rr][2] = __fmaf_rn(xv, w.z, acc1[rr][2]);
                    acc1[rr][3] = __fmaf_rn(xv, w.w, acc1[rr][3]);
                }
            }
        }
        const float4 bs = *(const float4*)&b_syn[h0];
#pragma unroll
        for (int rr = 0; rr < 4; ++rr) {
            float4 hv;
            hv.x = __fadd_rn(acc1[rr][0], bs.x);           // numpy's separate +b_syn
            hv.y = __fadd_rn(acc1[rr][1], bs.y);
            hv.z = __fadd_rn(acc1[rr][2], bs.z);
            hv.w = __fadd_rn(acc1[rr][3], bs.w);
            *(float4*)&hs[rg + rr][h0] = hv;
        }
    }
    __syncthreads();

    // ---- stage 2: 4x4 tile, sequential chain over j = 0..127 ----
    float acc[4][4];
#pragma unroll
    for (int rr = 0; rr < 4; ++rr)
#pragma unroll
        for (int q = 0; q < 4; ++q) acc[rr][q] = 0.0f;

#pragma unroll 8
    for (int j4 = 0; j4 < 32; ++j4) {
        float hrow[4][4];
#pragma unroll
        for (int rr = 0; rr < 4; ++rr) {
            float4 h4 = *(const float4*)&hs[rg + rr][4 * j4];
            hrow[rr][0] = h4.x; hrow[rr][1] = h4.y;
            hrow[rr][2] = h4.z; hrow[rr][3] = h4.w;
        }
#pragma unroll
        for (int q4 = 0; q4 < 4; ++q4) {                   // j ascending
            const int j = 4 * j4 + q4;
            float4 w = *(const float4*)&W_in[j * D_H + h0];
#pragma unroll
            for (int rr = 0; rr < 4; ++rr) {
                const float hv = hrow[rr][q4];
                acc[rr][0] = __fmaf_rn(hv, w.x, acc[rr][0]);
                acc[rr][1] = __fmaf_rn(hv, w.y, acc[rr][1]);
                acc[rr][2] = __fmaf_rn(hv, w.z, acc[rr][2]);
                acc[rr][3] = __fmaf_rn(hv, w.w, acc[rr][3]);
            }
        }
    }

    const float4 bi = *(const float4*)&b_in[h0];

    // ---- recurrence: uncontracted f32, I in registers ----
    const size_t BH = (size_t)B * D_H;
    float* __restrict__ vout = out + (size_t)L_STEPS * BH;

#pragma unroll
    for (int rr = 0; rr < 4; ++rr) {
        const float I0 = __fadd_rn(acc[rr][0], bi.x);      // numpy's separate +b_in
        const float I1 = __fadd_rn(acc[rr][1], bi.y);
        const float I2 = __fadd_rn(acc[rr][2], bi.z);
        const float I3 = __fadd_rn(acc[rr][3], bi.w);
        const size_t base = (size_t)(row0 + rg + rr) * D_H + (size_t)h0;
        float v0 = 0.f, v1 = 0.f, v2 = 0.f, v3 = 0.f;
        float s0 = 0.f, s1 = 0.f, s2 = 0.f, s3 = 0.f;
#pragma unroll
        for (int t = 0; t < L_STEPS; ++t) {
            v0 = __fsub_rn(__fadd_rn(__fmul_rn(0.9f, v0), I0), s0);
            v1 = __fsub_rn(__fadd_rn(__fmul_rn(0.9f, v1), I1), s1);
            v2 = __fsub_rn(__fadd_rn(__fmul_rn(0.9f, v2), I2), s2);
            v3 = __fsub_rn(__fadd_rn(__fmul_rn(0.9f, v3), I3), s3);
            s0 = (v0 >= 1.0f) ? 1.0f : 0.0f;
            s1 = (v1 >= 1.0f) ? 1.0f : 0.0f;
            s2 = (v2 >= 1.0f) ? 1.0f : 0.0f;
            s3 = (v3 >= 1.0f) ? 1.0f : 0.0f;
            f32x4 s4 = {s0, s1, s2, s3};
            *(f32x4*)(out + (size_t)t * BH + base) = s4;
        }
        f32x4 v4 = {v0, v1, v2, v3};
        *(f32x4*)(vout + base) = v4;
    }
}

extern "C" void kernel_launch(void* const* d_in, const int* in_sizes, int n_in,
                              void* d_out, int out_size, void* d_ws, size_t ws_size,
                              hipStream_t stream) {
    const float* x     = (const float*)d_in[0];
    const float* W_syn = (const float*)d_in[1];
    const float* b_syn = (const float*)d_in[2];
    const float* W_in  = (const float*)d_in[3];
    const float* b_in  = (const float*)d_in[4];
    float* out = (float*)d_out;

    const int B = in_sizes[0] / D_IN;   // 65536

    snn_fused<<<dim3(B / ROWS_PER_BLOCK), dim3(THREADS), 0, stream>>>(
        x, W_syn, b_syn, W_in, b_in, out, B);
}